// Round 3
// baseline (247.124 us; speedup 1.0000x reference)
//
#include <hip/hip_runtime.h>
#include <math.h>

// B=8, L=512, H=768, T=9, HEADS=12, d=64
//   Q = hs@Wq + bq ; K = hs@Wk + bk  (M=4096, N=6912, K=768)  -> RoPE -> bf16
//   score[b,i,j,t] = (1/96) * Qr[b*512+i, t*768:+768] . Kr[b*512+j, t*768:+768]
// R2: both GEMMs on the 256x256 8-phase schedule (T2 swizzle + counted vmcnt +
// setprio). 8 waves (2Mx4N), BK=64, 128KB LDS double-buffer, 12 K-tiles.

typedef __attribute__((ext_vector_type(4))) float f32x4;
typedef __attribute__((ext_vector_type(8))) __bf16 bf16x8;
typedef __attribute__((ext_vector_type(8))) unsigned short ushort8;

#define HH   768
#define NCOL 6912
#define LL   512
#define NT   12      // K-tiles of 64

static __device__ __forceinline__ unsigned short f2bf(float f) {
  unsigned int u = __float_as_uint(f);
  u += 0x7FFFu + ((u >> 16) & 1u);
  return (unsigned short)(u >> 16);
}

static __device__ __forceinline__ void async16(const void* g, void* l) {
  __builtin_amdgcn_global_load_lds(
      (const __attribute__((address_space(1))) unsigned int*)g,
      (__attribute__((address_space(3))) unsigned int*)l, 16, 0, 0);
}

// ---------------- prep kernels (unchanged from R1) ----------------

__global__ void k_conv_hs(const float4* __restrict__ in, ushort8* __restrict__ out) {
  int idx = blockIdx.x * 256 + threadIdx.x;
  float4 a = in[idx * 2], b = in[idx * 2 + 1];
  ushort8 o;
  o[0] = f2bf(a.x); o[1] = f2bf(a.y); o[2] = f2bf(a.z); o[3] = f2bf(a.w);
  o[4] = f2bf(b.x); o[5] = f2bf(b.y); o[6] = f2bf(b.z); o[7] = f2bf(b.w);
  out[idx] = o;
}

// W (768 x 6912) f32 -> Wt (6912 x 768) bf16, rows permuted for in-reg RoPE.
__global__ void k_transpose(const float* __restrict__ Wq, const float* __restrict__ Wk,
                            unsigned short* __restrict__ Wtq, unsigned short* __restrict__ Wtk) {
  __shared__ float tile[32][33];
  const float* W = blockIdx.z ? Wk : Wq;
  unsigned short* Wt = blockIdx.z ? Wtk : Wtq;
  int n0 = blockIdx.x * 32, k0 = blockIdx.y * 32;
  int tx = threadIdx.x, ty0 = threadIdx.y;
#pragma unroll
  for (int j = 0; j < 4; ++j) {
    int ty = ty0 + j * 8;
    tile[ty][tx] = W[(size_t)(k0 + ty) * NCOL + n0 + tx];
  }
  __syncthreads();
#pragma unroll
  for (int j = 0; j < 4; ++j) {
    int ty = ty0 + j * 8;
    int n = n0 + ty;
    int c = n & 63;
    int gc = ((c & 1) << 4) | ((c >> 5) << 5) | ((c & 31) >> 1);
    int np = (n & ~63) | gc;
    Wt[(size_t)np * HH + k0 + tx] = f2bf(tile[tx][ty]);
  }
}

__global__ void k_tables(float2* __restrict__ sc) {
  int idx = blockIdx.x * 256 + threadIdx.x;     // 16384
  int i = idx >> 5, p = idx & 31;
  double ang = (double)i * pow(10000.0, -(double)p / 32.0);
  sc[idx] = make_float2((float)sin(ang), (float)cos(ang));
}

// ---------------- 8-phase 256x256 K-loop (shared by both GEMMs) ----------------
// LDS per buffer: A 32KB (slot rows: sr -> m = (sr>>7)*64 + ((sr>>6)&1)*128 + (sr&63))
//                 B 32KB (slot rows: sr -> n = ((sr>>5)&3)*64 + (sr>>7)*32 + (sr&31))
// T2 swizzle: 16B chunk c at slot row sr stored at chunk (c ^ (sr&7)).
// Phases per K-tile: P0=(mq0,nq0)+read A0,B0; P1=(mq0,nq1)+read B1;
// P2=(mq1,nq0)+read A1; P3=(mq1,nq1). Stage 1 half-tile/phase, vmcnt(4) at P3.

template <int STRA, int STRB>
static __device__ __forceinline__ void k8_loop(
    const unsigned short* __restrict__ aSrc, const unsigned short* __restrict__ bSrc,
    char* smem, int tid, f32x4 acc[8][4]) {
  const int lane = tid & 63, wid = tid >> 6;
  const int wr = wid >> 2, wc = wid & 3;
  const int ldsW = wid * 1024;
  const int aRdBase = (wr * 64 + (lane & 15)) * 128;
  const int bRdBase = (wc * 32 + (lane & 15)) * 128;
  const int aci0 = (((lane >> 4)) ^ (lane & 7)) << 4;
  const int aci1 = ((4 + (lane >> 4)) ^ (lane & 7)) << 4;

  auto stageA = [&](int bb, int h, int kt) {
    const unsigned short* g = aSrc + (size_t)(h * 64) * STRA + kt * 64;
    char* l = smem + bb * 65536 + h * 16384 + ldsW;
    async16(g, l);
    async16(g + (size_t)128 * STRA, l + 8192);
  };
  auto stageB = [&](int bb, int h, int kt) {
    const unsigned short* g = bSrc + (size_t)(h * 32) * STRB + kt * 64;
    char* l = smem + bb * 65536 + 32768 + h * 16384 + ldsW;
    async16(g, l);
    async16(g + (size_t)128 * STRB, l + 8192);
  };

  // prologue: tile0 fully, tile1 h0 halves; leave 4 loads in flight
  stageA(0, 0, 0); stageA(0, 1, 0); stageB(0, 0, 0); stageB(0, 1, 0);
  stageA(1, 0, 1); stageB(1, 0, 1);
  asm volatile("s_waitcnt vmcnt(4)" ::: "memory");
  __builtin_amdgcn_s_barrier();

  int cur = 0;
  for (int t = 0; t < NT; ++t) {
    const int nxt = cur ^ 1;
    const int k1 = (t + 1 < NT) ? t + 1 : NT - 1;
    const int k2 = (t + 2 < NT) ? t + 2 : NT - 1;
    char* AB = smem + cur * 65536;
    char* BB = AB + 32768;
    bf16x8 af[4][2], b0[2][2], b1[2][2];

    // ---- P0: quadrant (mq0, nq0) ----
#pragma unroll
    for (int mfi = 0; mfi < 4; ++mfi) {
      af[mfi][0] = *(const bf16x8*)(AB + aRdBase + mfi * 2048 + aci0);
      af[mfi][1] = *(const bf16x8*)(AB + aRdBase + mfi * 2048 + aci1);
    }
#pragma unroll
    for (int nf = 0; nf < 2; ++nf) {
      b0[nf][0] = *(const bf16x8*)(BB + bRdBase + nf * 2048 + aci0);
      b0[nf][1] = *(const bf16x8*)(BB + bRdBase + nf * 2048 + aci1);
    }
    stageA(nxt, 1, k1);
    __builtin_amdgcn_s_barrier();
    asm volatile("s_waitcnt lgkmcnt(0)" ::: "memory");
    __builtin_amdgcn_s_setprio(1);
#pragma unroll
    for (int kk = 0; kk < 2; ++kk)
#pragma unroll
      for (int mfi = 0; mfi < 4; ++mfi)
#pragma unroll
        for (int nf = 0; nf < 2; ++nf)
          acc[mfi][nf] = __builtin_amdgcn_mfma_f32_16x16x32_bf16(af[mfi][kk], b0[nf][kk], acc[mfi][nf], 0, 0, 0);
    __builtin_amdgcn_s_setprio(0);
    __builtin_amdgcn_s_barrier();

    // ---- P1: quadrant (mq0, nq1) ----
#pragma unroll
    for (int nf = 0; nf < 2; ++nf) {
      b1[nf][0] = *(const bf16x8*)(BB + 16384 + bRdBase + nf * 2048 + aci0);
      b1[nf][1] = *(const bf16x8*)(BB + 16384 + bRdBase + nf * 2048 + aci1);
    }
    stageB(nxt, 1, k1);
    __builtin_amdgcn_s_barrier();
    asm volatile("s_waitcnt lgkmcnt(0)" ::: "memory");
    __builtin_amdgcn_s_setprio(1);
#pragma unroll
    for (int kk = 0; kk < 2; ++kk)
#pragma unroll
      for (int mfi = 0; mfi < 4; ++mfi)
#pragma unroll
        for (int nf = 0; nf < 2; ++nf)
          acc[mfi][2 + nf] = __builtin_amdgcn_mfma_f32_16x16x32_bf16(af[mfi][kk], b1[nf][kk], acc[mfi][2 + nf], 0, 0, 0);
    __builtin_amdgcn_s_setprio(0);
    __builtin_amdgcn_s_barrier();

    // ---- P2: quadrant (mq1, nq0) ----
#pragma unroll
    for (int mfi = 0; mfi < 4; ++mfi) {
      af[mfi][0] = *(const bf16x8*)(AB + 16384 + aRdBase + mfi * 2048 + aci0);
      af[mfi][1] = *(const bf16x8*)(AB + 16384 + aRdBase + mfi * 2048 + aci1);
    }
    stageA(cur, 0, k2);
    __builtin_amdgcn_s_barrier();
    asm volatile("s_waitcnt lgkmcnt(0)" ::: "memory");
    __builtin_amdgcn_s_setprio(1);
#pragma unroll
    for (int kk = 0; kk < 2; ++kk)
#pragma unroll
      for (int mfi = 0; mfi < 4; ++mfi)
#pragma unroll
        for (int nf = 0; nf < 2; ++nf)
          acc[4 + mfi][nf] = __builtin_amdgcn_mfma_f32_16x16x32_bf16(af[mfi][kk], b0[nf][kk], acc[4 + mfi][nf], 0, 0, 0);
    __builtin_amdgcn_s_setprio(0);
    __builtin_amdgcn_s_barrier();

    // ---- P3: quadrant (mq1, nq1) ----
    stageB(cur, 0, k2);
    __builtin_amdgcn_s_barrier();
    __builtin_amdgcn_s_setprio(1);
#pragma unroll
    for (int kk = 0; kk < 2; ++kk)
#pragma unroll
      for (int mfi = 0; mfi < 4; ++mfi)
#pragma unroll
        for (int nf = 0; nf < 2; ++nf)
          acc[4 + mfi][2 + nf] = __builtin_amdgcn_mfma_f32_16x16x32_bf16(af[mfi][kk], b1[nf][kk], acc[4 + mfi][2 + nf], 0, 0, 0);
    __builtin_amdgcn_s_setprio(0);
    asm volatile("s_waitcnt vmcnt(4)" ::: "memory");
    __builtin_amdgcn_s_barrier();
    cur = nxt;
  }
}

// ---------------- GEMM1: projection + bias + RoPE -> bf16 ----------------

__global__ __launch_bounds__(512, 2) void k8_rope(
    const unsigned short* __restrict__ hsb,
    const unsigned short* __restrict__ Wtq, const unsigned short* __restrict__ Wtk,
    const float* __restrict__ bq, const float* __restrict__ bk,
    const float2* __restrict__ sc,
    unsigned short* __restrict__ Qr, unsigned short* __restrict__ Kr) {
  __shared__ __align__(16) char smem[131072];
  const int bid = blockIdx.x;                 // 864 = 27n * 16m * 2z
  const int swz = (bid & 7) * 108 + (bid >> 3);
  const int ntile = swz % 27;
  const int rest = swz / 27;
  const int mtile = rest & 15, zz = rest >> 4;
  const unsigned short* Wt = zz ? Wtk : Wtq;
  const float* bias = zz ? bk : bq;
  unsigned short* outp = zz ? Kr : Qr;
  const int m0 = mtile * 256, n0 = ntile * 256;
  const int tid = threadIdx.x;

  const int row_in = tid >> 3;
  const int ci_u = (tid & 7) ^ (row_in & 7);
  const unsigned short* aSrc = hsb + (size_t)(m0 + row_in) * HH + ci_u * 8;
  const unsigned short* bSrc = Wt + (size_t)(n0 + (row_in >> 5) * 64 + (row_in & 31)) * HH + ci_u * 8;

  f32x4 acc[8][4] = {};
  k8_loop<HH, HH>(aSrc, bSrc, smem, tid, acc);

  const int lane = tid & 63, wid = tid >> 6;
  const int wr = wid >> 2, wc = wid & 3;
  const int cA = n0 + wc * 64;
  const int e0 = lane & 15, e1 = 16 + e0;
  const float b1a = bias[cA + 2 * e0], b2a = bias[cA + 2 * e0 + 1];
  const float b1b = bias[cA + 2 * e1], b2b = bias[cA + 2 * e1 + 1];

#pragma unroll
  for (int mf = 0; mf < 8; ++mf) {
    const int rbase = m0 + wr * 128 + (mf >> 2) * 64 + (mf & 3) * 16 + (lane >> 4) * 4;
#pragma unroll
    for (int q = 0; q < 4; ++q) {
      const int grow = rbase + q;
      const int i = grow & (LL - 1);
      float2 s0 = sc[i * 32 + e0];
      float2 s1 = sc[i * 32 + e1];
      float x1 = acc[mf][0][q] + b1a, x2 = acc[mf][1][q] + b2a;
      float y1 = acc[mf][2][q] + b1b, y2 = acc[mf][3][q] + b2b;
      size_t ro = (size_t)grow * NCOL + cA;
      outp[ro + e0]      = f2bf(x1 * s0.y - x2 * s0.x);
      outp[ro + e0 + 32] = f2bf(x2 * s0.y + x1 * s0.x);
      outp[ro + e1]      = f2bf(y1 * s1.y - y2 * s1.x);
      outp[ro + e1 + 32] = f2bf(y2 * s1.y + y1 * s1.x);
    }
  }
}

// ---------------- GEMM2: score ----------------

__global__ __launch_bounds__(512, 2) void k8_score(
    const unsigned short* __restrict__ Qr, const unsigned short* __restrict__ Kr,
    float* __restrict__ out) {
  __shared__ __align__(16) char smem[131072];
  const int bid = blockIdx.x;                 // 288 = 9t * 2jt * 2it * 8b
  const int swz = (bid & 7) * 36 + (bid >> 3);
  const int t = swz % 9;
  const int r2 = swz / 9;
  const int jt = r2 & 1, it = (r2 >> 1) & 1, b = r2 >> 2;
  const int tid = threadIdx.x;

  const int row_in = tid >> 3;
  const int ci_u = (tid & 7) ^ (row_in & 7);
  const unsigned short* aSrc = Qr + (size_t)(b * 512 + it * 256 + row_in) * NCOL + t * HH + ci_u * 8;
  const unsigned short* bSrc = Kr + (size_t)(b * 512 + jt * 256 + (row_in >> 5) * 64 + (row_in & 31)) * NCOL + t * HH + ci_u * 8;

  f32x4 acc[8][4] = {};
  k8_loop<NCOL, NCOL>(aSrc, bSrc, smem, tid, acc);

  const int lane = tid & 63, wid = tid >> 6;
  const int wr = wid >> 2, wc = wid & 3;
  const float SC = 0.125f / 12.0f;
#pragma unroll
  for (int mf = 0; mf < 8; ++mf) {
    const int i0 = it * 256 + wr * 128 + (mf >> 2) * 64 + (mf & 3) * 16 + (lane >> 4) * 4;
#pragma unroll
    for (int nf = 0; nf < 4; ++nf) {
      const int j = jt * 256 + wc * 64 + nf * 16 + (lane & 15);
#pragma unroll
      for (int q = 0; q < 4; ++q) {
        size_t o = ((size_t)(b * 512 + i0 + q) * 512 + j) * 9 + t;
        out[o] = acc[mf][nf][q] * SC;
      }
    }
  }
}

// ---------------- launch ----------------

extern "C" void kernel_launch(void* const* d_in, const int* in_sizes, int n_in,
                              void* d_out, int out_size, void* d_ws, size_t ws_size,
                              hipStream_t stream) {
  const float* hs = (const float*)d_in[0];
  const float* Wq = (const float*)d_in[1];
  const float* bq = (const float*)d_in[2];
  const float* Wk = (const float*)d_in[3];
  const float* bk = (const float*)d_in[4];
  float* out = (float*)d_out;
  char* ws = (char*)d_ws;

  float2* sctab = (float2*)(ws);                               //  131072
  unsigned short* hsb = (unsigned short*)(ws + 131072);        // 6291456
  unsigned short* Wtq = (unsigned short*)(ws + 6422528);       // 10616832
  unsigned short* Wtk = (unsigned short*)(ws + 17039360);      // 10616832
  unsigned short* Qr  = (unsigned short*)(ws + 27656192);      // 56623104
  unsigned short* Kr  = (unsigned short*)(ws + 84279296);      // 56623104 -> 140902400

  hipLaunchKernelGGL(k_conv_hs, dim3(1536), dim3(256), 0, stream,
                     (const float4*)hs, (ushort8*)hsb);
  hipLaunchKernelGGL(k_transpose, dim3(216, 24, 2), dim3(32, 8), 0, stream,
                     Wq, Wk, Wtq, Wtk);
  hipLaunchKernelGGL(k_tables, dim3(64), dim3(256), 0, stream, sctab);
  hipLaunchKernelGGL(k8_rope, dim3(864), dim3(512), 0, stream,
                     hsb, Wtq, Wtk, bq, bk, sctab, Qr, Kr);
  hipLaunchKernelGGL(k8_score, dim3(288), dim3(512), 0, stream, Qr, Kr, out);
}

// Round 5
// 244.574 us; speedup vs baseline: 1.0104x; 1.0104x over previous
//
#include <hip/hip_runtime.h>
#include <math.h>

// B=8, L=512, H=768, T=9, HEADS=12, d=64
//   Q = hs@Wq + bq ; K = hs@Wk + bk  (M=4096, N=6912, K=768)  -> RoPE -> bf16
//   score[b,i,j,t] = (1/96) * Qr[b*512+i, t*768:+768] . Kr[b*512+j, t*768:+768]
// R4: R3's pipelined 8-phase schedule + race fix: the vmcnt(4) covering the
// next-tile h0 staging is moved to END of P1 (one barrier BEFORE P2's
// cross-wave RD_B), and ds_read groups are pinned with sched_barrier(0).

typedef __attribute__((ext_vector_type(4))) float f32x4;
typedef __attribute__((ext_vector_type(8))) __bf16 bf16x8;
typedef __attribute__((ext_vector_type(8))) unsigned short ushort8;

#define HH   768
#define NCOL 6912
#define LL   512
#define NT   12      // K-tiles of 64

static __device__ __forceinline__ unsigned short f2bf(float f) {
  unsigned int u = __float_as_uint(f);
  u += 0x7FFFu + ((u >> 16) & 1u);
  return (unsigned short)(u >> 16);
}

static __device__ __forceinline__ void async16(const void* g, void* l) {
  __builtin_amdgcn_global_load_lds(
      (const __attribute__((address_space(1))) unsigned int*)g,
      (__attribute__((address_space(3))) unsigned int*)l, 16, 0, 0);
}

// ---------------- prep kernels ----------------

__global__ void k_conv_hs(const float4* __restrict__ in, ushort8* __restrict__ out) {
  int idx = blockIdx.x * 256 + threadIdx.x;
  float4 a = in[idx * 2], b = in[idx * 2 + 1];
  ushort8 o;
  o[0] = f2bf(a.x); o[1] = f2bf(a.y); o[2] = f2bf(a.z); o[3] = f2bf(a.w);
  o[4] = f2bf(b.x); o[5] = f2bf(b.y); o[6] = f2bf(b.z); o[7] = f2bf(b.w);
  out[idx] = o;
}

// W (768 x 6912) f32 -> Wt (6912 x 768) bf16, rows permuted for in-reg RoPE.
__global__ void k_transpose(const float* __restrict__ Wq, const float* __restrict__ Wk,
                            unsigned short* __restrict__ Wtq, unsigned short* __restrict__ Wtk) {
  __shared__ float tile[32][33];
  const float* W = blockIdx.z ? Wk : Wq;
  unsigned short* Wt = blockIdx.z ? Wtk : Wtq;
  int n0 = blockIdx.x * 32, k0 = blockIdx.y * 32;
  int tx = threadIdx.x, ty0 = threadIdx.y;
#pragma unroll
  for (int j = 0; j < 4; ++j) {
    int ty = ty0 + j * 8;
    tile[ty][tx] = W[(size_t)(k0 + ty) * NCOL + n0 + tx];
  }
  __syncthreads();
#pragma unroll
  for (int j = 0; j < 4; ++j) {
    int ty = ty0 + j * 8;
    int n = n0 + ty;
    int c = n & 63;
    int gc = ((c & 1) << 4) | ((c >> 5) << 5) | ((c & 31) >> 1);
    int np = (n & ~63) | gc;
    Wt[(size_t)np * HH + k0 + tx] = f2bf(tile[tx][ty]);
  }
}

__global__ void k_tables(float2* __restrict__ sc) {
  int idx = blockIdx.x * 256 + threadIdx.x;     // 16384
  int i = idx >> 5, p = idx & 31;
  double ang = (double)i * pow(10000.0, -(double)p / 32.0);
  sc[idx] = make_float2((float)sin(ang), (float)cos(ang));
}

// ---------------- pipelined 8-phase 256x256 K-loop ----------------

#define RD_A(dst, bp) do { \
  _Pragma("unroll") for (int mfi = 0; mfi < 4; ++mfi) { \
    dst[mfi][0] = *(const bf16x8*)((bp) + aRdBase + mfi * 2048 + aci0); \
    dst[mfi][1] = *(const bf16x8*)((bp) + aRdBase + mfi * 2048 + aci1); } \
  __builtin_amdgcn_sched_barrier(0); } while (0)

#define RD_B(dst, bp) do { \
  _Pragma("unroll") for (int nf = 0; nf < 2; ++nf) { \
    dst[nf][0] = *(const bf16x8*)((bp) + bRdBase + nf * 2048 + aci0); \
    dst[nf][1] = *(const bf16x8*)((bp) + bRdBase + nf * 2048 + aci1); } \
  __builtin_amdgcn_sched_barrier(0); } while (0)

#define MM(Ar, Br, mo, no) do { \
  _Pragma("unroll") for (int kk = 0; kk < 2; ++kk) \
  _Pragma("unroll") for (int mfi = 0; mfi < 4; ++mfi) \
  _Pragma("unroll") for (int nf = 0; nf < 2; ++nf) \
    acc[(mo) + mfi][(no) + nf] = __builtin_amdgcn_mfma_f32_16x16x32_bf16( \
        Ar[mfi][kk], Br[nf][kk], acc[(mo) + mfi][(no) + nf], 0, 0, 0); } while (0)

#define TILE(B0u, B0o, CUR, T) do { \
  const int k1 = ((T) + 1 < NT) ? (T) + 1 : NT - 1; \
  const int k2 = ((T) + 2 < NT) ? (T) + 2 : NT - 1; \
  char* AB = smem + (CUR) * 65536;  char* BB = AB + 32768; \
  char* ABn = smem + ((CUR) ^ 1) * 65536;  char* BBn = ABn + 32768; \
  /* P0: mfma(Aa,B0u); read B1 (for P1) */ \
  RD_B(B1, BB + 16384); \
  stageA((CUR) ^ 1, 1, k1); \
  __builtin_amdgcn_s_barrier(); \
  asm volatile("s_waitcnt lgkmcnt(4)" ::: "memory"); \
  __builtin_amdgcn_sched_barrier(0); \
  __builtin_amdgcn_s_setprio(1); MM(Aa, B0u, 0, 0); \
  __builtin_amdgcn_sched_barrier(0); __builtin_amdgcn_s_setprio(0); \
  __builtin_amdgcn_s_barrier(); \
  /* P1: mfma(Aa,B1); read Ab (for P2); end: vmcnt(4) retires next-tile h0 */ \
  RD_A(Ab, AB + 16384); \
  stageB((CUR) ^ 1, 1, k1); \
  __builtin_amdgcn_s_barrier(); \
  asm volatile("s_waitcnt lgkmcnt(8)" ::: "memory"); \
  __builtin_amdgcn_sched_barrier(0); \
  __builtin_amdgcn_s_setprio(1); MM(Aa, B1, 0, 2); \
  __builtin_amdgcn_sched_barrier(0); __builtin_amdgcn_s_setprio(0); \
  asm volatile("s_waitcnt vmcnt(4)" ::: "memory"); \
  __builtin_amdgcn_s_barrier(); \
  /* P2: mfma(Ab,B0u); read B0o = B0(t+1) (for next P0) */ \
  RD_B(B0o, BBn); \
  stageA(CUR, 0, k2); \
  __builtin_amdgcn_s_barrier(); \
  asm volatile("s_waitcnt lgkmcnt(4)" ::: "memory"); \
  __builtin_amdgcn_sched_barrier(0); \
  __builtin_amdgcn_s_setprio(1); MM(Ab, B0u, 4, 0); \
  __builtin_amdgcn_sched_barrier(0); __builtin_amdgcn_s_setprio(0); \
  __builtin_amdgcn_s_barrier(); \
  /* P3: mfma(Ab,B1); read Aa = A0(t+1) (for next P0) */ \
  RD_A(Aa, ABn); \
  stageB(CUR, 0, k2); \
  asm volatile("s_waitcnt vmcnt(4)" ::: "memory"); \
  __builtin_amdgcn_s_barrier(); \
  asm volatile("s_waitcnt lgkmcnt(8)" ::: "memory"); \
  __builtin_amdgcn_sched_barrier(0); \
  __builtin_amdgcn_s_setprio(1); MM(Ab, B1, 4, 2); \
  __builtin_amdgcn_sched_barrier(0); __builtin_amdgcn_s_setprio(0); \
  __builtin_amdgcn_s_barrier(); \
} while (0)

template <int STRA, int STRB>
static __device__ __forceinline__ void k8_loop(
    const unsigned short* __restrict__ aSrc, const unsigned short* __restrict__ bSrc,
    char* smem, int tid, f32x4 acc[8][4]) {
  const int lane = tid & 63, wid = tid >> 6;
  const int wr = wid >> 2, wc = wid & 3;
  const int ldsW = wid * 1024;
  const int aRdBase = (wr * 64 + (lane & 15)) * 128;
  const int bRdBase = (wc * 32 + (lane & 15)) * 128;
  const int aci0 = ((lane >> 4) ^ (lane & 7)) << 4;
  const int aci1 = ((4 + (lane >> 4)) ^ (lane & 7)) << 4;

  auto stageA = [&](int bb, int h, int kt) {
    const unsigned short* g = aSrc + (size_t)(h * 64) * STRA + kt * 64;
    char* l = smem + bb * 65536 + h * 16384 + ldsW;
    async16(g, l);
    async16(g + (size_t)128 * STRA, l + 8192);
  };
  auto stageB = [&](int bb, int h, int kt) {
    const unsigned short* g = bSrc + (size_t)(h * 32) * STRB + kt * 64;
    char* l = smem + bb * 65536 + 32768 + h * 16384 + ldsW;
    async16(g, l);
    async16(g + (size_t)128 * STRB, l + 8192);
  };

  bf16x8 Aa[4][2], Ab[4][2], B0a[2][2], B0b[2][2], B1[2][2];

  // prologue: tile0 full + tile1 h0; then first-phase operands into regs
  stageA(0, 0, 0); stageA(0, 1, 0); stageB(0, 0, 0); stageB(0, 1, 0);
  stageA(1, 0, 1); stageB(1, 0, 1);
  asm volatile("s_waitcnt vmcnt(4)" ::: "memory");
  __builtin_amdgcn_s_barrier();
  RD_A(Aa, smem);
  RD_B(B0a, smem + 32768);
  asm volatile("s_waitcnt lgkmcnt(0)" ::: "memory");
  __builtin_amdgcn_sched_barrier(0);

  for (int t = 0; t < NT; t += 2) {
    TILE(B0a, B0b, 0, t);
    TILE(B0b, B0a, 1, t + 1);
  }
}

// ---------------- GEMM1: projection + bias + RoPE -> bf16 ----------------

__global__ __launch_bounds__(512, 2) void k8_rope(
    const unsigned short* __restrict__ hsb,
    const unsigned short* __restrict__ Wtq, const unsigned short* __restrict__ Wtk,
    const float* __restrict__ bq, const float* __restrict__ bk,
    const float2* __restrict__ sc,
    unsigned short* __restrict__ Qr, unsigned short* __restrict__ Kr) {
  __shared__ __align__(16) char smem[131072];
  const int bid = blockIdx.x;                 // 864 = 27n * 16m * 2z
  const int swz = (bid & 7) * 108 + (bid >> 3);
  const int ntile = swz % 27;
  const int rest = swz / 27;
  const int mtile = rest & 15, zz = rest >> 4;
  const unsigned short* Wt = zz ? Wtk : Wtq;
  const float* bias = zz ? bk : bq;
  unsigned short* outp = zz ? Kr : Qr;
  const int m0 = mtile * 256, n0 = ntile * 256;
  const int tid = threadIdx.x;

  const int row_in = tid >> 3;
  const int ci_u = (tid & 7) ^ (row_in & 7);
  const unsigned short* aSrc = hsb + (size_t)(m0 + row_in) * HH + ci_u * 8;
  const unsigned short* bSrc = Wt + (size_t)(n0 + (row_in >> 5) * 64 + (row_in & 31)) * HH + ci_u * 8;

  f32x4 acc[8][4] = {};
  k8_loop<HH, HH>(aSrc, bSrc, smem, tid, acc);

  const int lane = tid & 63, wid = tid >> 6;
  const int wr = wid >> 2, wc = wid & 3;
  const int cA = n0 + wc * 64;
  const int e0 = lane & 15, e1 = 16 + e0;
  const float b1a = bias[cA + 2 * e0], b2a = bias[cA + 2 * e0 + 1];
  const float b1b = bias[cA + 2 * e1], b2b = bias[cA + 2 * e1 + 1];

#pragma unroll
  for (int mf = 0; mf < 8; ++mf) {
    const int rbase = m0 + wr * 128 + (mf >> 2) * 64 + (mf & 3) * 16 + (lane >> 4) * 4;
#pragma unroll
    for (int q = 0; q < 4; ++q) {
      const int grow = rbase + q;
      const int i = grow & (LL - 1);
      float2 s0 = sc[i * 32 + e0];
      float2 s1 = sc[i * 32 + e1];
      float x1 = acc[mf][0][q] + b1a, x2 = acc[mf][1][q] + b2a;
      float y1 = acc[mf][2][q] + b1b, y2 = acc[mf][3][q] + b2b;
      size_t ro = (size_t)grow * NCOL + cA;
      outp[ro + e0]      = f2bf(x1 * s0.y - x2 * s0.x);
      outp[ro + e0 + 32] = f2bf(x2 * s0.y + x1 * s0.x);
      outp[ro + e1]      = f2bf(y1 * s1.y - y2 * s1.x);
      outp[ro + e1 + 32] = f2bf(y2 * s1.y + y1 * s1.x);
    }
  }
}

// ---------------- GEMM2: score ----------------

__global__ __launch_bounds__(512, 2) void k8_score(
    const unsigned short* __restrict__ Qr, const unsigned short* __restrict__ Kr,
    float* __restrict__ out) {
  __shared__ __align__(16) char smem[131072];
  const int bid = blockIdx.x;                 // 288 = 9t * 2jt * 2it * 8b
  const int swz = (bid & 7) * 36 + (bid >> 3);
  const int t = swz % 9;
  const int r2 = swz / 9;
  const int jt = r2 & 1, it = (r2 >> 1) & 1, b = r2 >> 2;
  const int tid = threadIdx.x;

  const int row_in = tid >> 3;
  const int ci_u = (tid & 7) ^ (row_in & 7);
  const unsigned short* aSrc = Qr + (size_t)(b * 512 + it * 256 + row_in) * NCOL + t * HH + ci_u * 8;
  const unsigned short* bSrc = Kr + (size_t)(b * 512 + jt * 256 + (row_in >> 5) * 64 + (row_in & 31)) * NCOL + t * HH + ci_u * 8;

  f32x4 acc[8][4] = {};
  k8_loop<NCOL, NCOL>(aSrc, bSrc, smem, tid, acc);

  const int lane = tid & 63, wid = tid >> 6;
  const int wr = wid >> 2, wc = wid & 3;
  const float SC = 0.125f / 12.0f;
#pragma unroll
  for (int mf = 0; mf < 8; ++mf) {
    const int i0 = it * 256 + wr * 128 + (mf >> 2) * 64 + (mf & 3) * 16 + (lane >> 4) * 4;
#pragma unroll
    for (int nf = 0; nf < 4; ++nf) {
      const int j = jt * 256 + wc * 64 + nf * 16 + (lane & 15);
#pragma unroll
      for (int q = 0; q < 4; ++q) {
        size_t o = ((size_t)(b * 512 + i0 + q) * 512 + j) * 9 + t;
        out[o] = acc[mf][nf][q] * SC;
      }
    }
  }
}

// ---------------- launch ----------------

extern "C" void kernel_launch(void* const* d_in, const int* in_sizes, int n_in,
                              void* d_out, int out_size, void* d_ws, size_t ws_size,
                              hipStream_t stream) {
  const float* hs = (const float*)d_in[0];
  const float* Wq = (const float*)d_in[1];
  const float* bq = (const float*)d_in[2];
  const float* Wk = (const float*)d_in[3];
  const float* bk = (const float*)d_in[4];
  float* out = (float*)d_out;
  char* ws = (char*)d_ws;

  float2* sctab = (float2*)(ws);                               //  131072
  unsigned short* hsb = (unsigned short*)(ws + 131072);        // 6291456
  unsigned short* Wtq = (unsigned short*)(ws + 6422528);       // 10616832
  unsigned short* Wtk = (unsigned short*)(ws + 17039360);      // 10616832
  unsigned short* Qr  = (unsigned short*)(ws + 27656192);      // 56623104
  unsigned short* Kr  = (unsigned short*)(ws + 84279296);      // 56623104 -> 140902400

  hipLaunchKernelGGL(k_conv_hs, dim3(1536), dim3(256), 0, stream,
                     (const float4*)hs, (ushort8*)hsb);
  hipLaunchKernelGGL(k_transpose, dim3(216, 24, 2), dim3(32, 8), 0, stream,
                     Wq, Wk, Wtq, Wtk);
  hipLaunchKernelGGL(k_tables, dim3(64), dim3(256), 0, stream, sctab);
  hipLaunchKernelGGL(k8_rope, dim3(864), dim3(512), 0, stream,
                     hsb, Wtq, Wtk, bq, bk, sctab, Qr, Kr);
  hipLaunchKernelGGL(k8_score, dim3(288), dim3(512), 0, stream, Qr, Kr, out);
}